// Round 1
// baseline (232.107 us; speedup 1.0000x reference)
//
#include <hip/hip_runtime.h>
#include <math.h>

// Problem constants
#define B 2
#define L 2048
#define D 512
#define H 8
#define HD 64
#define W2 128            // WINDOW/2
#define NOUT (3*D)        // 1536 (Q|K|V concatenated)

// Truncation: pw[l] ~ exp(-0.1*(2047-l)); seqlen in [1920,2048].
// Queries below QS have relative weight <= e^-38 -> negligible vs 1.6e-2 threshold.
#define QS 1664
#define NQ (L - QS)       // 384 queries per batch
#define ROWS0 (QS - W2)   // 1536: lowest key row needed
#define NROWS (L - ROWS0) // 512 LN/QKV rows per batch
#define MROWS (B * NROWS) // 1024

// ---------------- LayerNorm: one wave per row ----------------
__global__ __launch_bounds__(64) void ln_kernel(const float* __restrict__ seq,
                                                const float* __restrict__ gamma,
                                                const float* __restrict__ beta,
                                                float* __restrict__ x) {
    int row = blockIdx.x;           // 0..MROWS-1
    int b = row / NROWS;
    int l = ROWS0 + (row - b * NROWS);
    const float* src = seq + ((size_t)b * L + l) * D;
    int lane = threadIdx.x;
    float4 v0 = ((const float4*)src)[lane];
    float4 v1 = ((const float4*)src)[lane + 64];
    float s  = v0.x + v0.y + v0.z + v0.w + v1.x + v1.y + v1.z + v1.w;
    float sq = v0.x*v0.x + v0.y*v0.y + v0.z*v0.z + v0.w*v0.w
             + v1.x*v1.x + v1.y*v1.y + v1.z*v1.z + v1.w*v1.w;
    for (int o = 32; o; o >>= 1) { s += __shfl_xor(s, o); sq += __shfl_xor(sq, o); }
    float mu = s * (1.0f / D);
    float var = sq * (1.0f / D) - mu * mu;
    float rstd = rsqrtf(var + 1e-5f);
    float4 g0 = ((const float4*)gamma)[lane];
    float4 g1 = ((const float4*)gamma)[lane + 64];
    float4 b0 = ((const float4*)beta)[lane];
    float4 b1 = ((const float4*)beta)[lane + 64];
    float4 o0, o1;
    o0.x = (v0.x - mu) * rstd * g0.x + b0.x;
    o0.y = (v0.y - mu) * rstd * g0.y + b0.y;
    o0.z = (v0.z - mu) * rstd * g0.z + b0.z;
    o0.w = (v0.w - mu) * rstd * g0.w + b0.w;
    o1.x = (v1.x - mu) * rstd * g1.x + b1.x;
    o1.y = (v1.y - mu) * rstd * g1.y + b1.y;
    o1.z = (v1.z - mu) * rstd * g1.z + b1.z;
    o1.w = (v1.w - mu) * rstd * g1.w + b1.w;
    float* dst = x + (size_t)row * D;
    ((float4*)dst)[lane] = o0;
    ((float4*)dst)[lane + 64] = o1;
}

// ---------------- QKV GEMM: C[m, o] = sum_d x[m,d] * W[o,d] ----------------
// M=1024, N=1536 (Wq|Wk|Wv), K=512. 64x64 tile, 256 threads, 4x4/thread, BK=16.
#define BM 64
#define BN 64
#define BK 16
#define LDP (BM + 4)   // LDS stride 68 floats: keeps float4 alignment, breaks pow2 banks

__global__ __launch_bounds__(256) void qkv_gemm(const float* __restrict__ x,
                                                const float* __restrict__ Wq,
                                                const float* __restrict__ Wk,
                                                const float* __restrict__ Wv,
                                                float* __restrict__ qkv) {
    __shared__ float As[BK][LDP];
    __shared__ float Bs[BK][LDP];
    int tid = threadIdx.x;
    int m0 = blockIdx.x * BM;
    int n0 = blockIdx.y * BN;
    const float* Wsel = (n0 < D) ? Wq : (n0 < 2 * D ? Wk : Wv);
    int ob = n0 & (D - 1);
    int lr = tid >> 2;           // 0..63: row within tile
    int lc = (tid & 3) * 4;      // 0,4,8,12: col (float4)
    const float* aptr = x + (size_t)(m0 + lr) * D + lc;
    const float* bptr = Wsel + (size_t)(ob + lr) * D + lc;
    int ty = tid >> 4, tx = tid & 15;
    float acc[4][4] = {};
    for (int kt = 0; kt < D; kt += BK) {
        float4 av = *(const float4*)(aptr + kt);
        float4 bv = *(const float4*)(bptr + kt);
        __syncthreads();
        As[lc + 0][lr] = av.x; As[lc + 1][lr] = av.y;
        As[lc + 2][lr] = av.z; As[lc + 3][lr] = av.w;
        Bs[lc + 0][lr] = bv.x; Bs[lc + 1][lr] = bv.y;
        Bs[lc + 2][lr] = bv.z; Bs[lc + 3][lr] = bv.w;
        __syncthreads();
#pragma unroll
        for (int k = 0; k < BK; ++k) {
            float4 a = *(const float4*)&As[k][ty * 4];
            float4 bb = *(const float4*)&Bs[k][tx * 4];
            acc[0][0] += a.x * bb.x; acc[0][1] += a.x * bb.y; acc[0][2] += a.x * bb.z; acc[0][3] += a.x * bb.w;
            acc[1][0] += a.y * bb.x; acc[1][1] += a.y * bb.y; acc[1][2] += a.y * bb.z; acc[1][3] += a.y * bb.w;
            acc[2][0] += a.z * bb.x; acc[2][1] += a.z * bb.y; acc[2][2] += a.z * bb.z; acc[2][3] += a.z * bb.w;
            acc[3][0] += a.w * bb.x; acc[3][1] += a.w * bb.y; acc[3][2] += a.w * bb.z; acc[3][3] += a.w * bb.w;
        }
    }
#pragma unroll
    for (int i = 0; i < 4; ++i) {
        float4 o = make_float4(acc[i][0], acc[i][1], acc[i][2], acc[i][3]);
        *(float4*)(qkv + (size_t)(m0 + ty * 4 + i) * NOUT + n0 + tx * 4) = o;
    }
}

// ---------------- Attention: 1 wave per (head), 4 heads per block ----------------
// grid = B * NQ * 2, block = 256 (4 waves); wave w handles head hg*4+w of query q.
__global__ __launch_bounds__(256) void attn_kernel(const float* __restrict__ qkv,
                                                   const float* __restrict__ ts,
                                                   const int* __restrict__ slen,
                                                   const float* __restrict__ tw,
                                                   float* __restrict__ att) {
    int bid = blockIdx.x;
    int b = bid / (NQ * 2);
    int rem = bid - b * (NQ * 2);
    int qi = rem >> 1;
    int hg = rem & 1;
    int wid = threadIdx.x >> 6;
    int lane = threadIdx.x & 63;
    int h = hg * 4 + wid;
    int q = QS + qi;
    int sl = slen[b];
    float* myout = att + ((size_t)(b * NQ + qi)) * D + h * HD + lane;
    if (q >= sl) { *myout = 0.0f; return; }   // uniform per block

    __shared__ float sc[4][264];
    __shared__ float qv[4][64];

    int kmin = q - W2;                      // >= ROWS0 by construction
    int kmax = min(q + W2, sl - 1);
    int nk = kmax - kmin + 1;               // in [129, 257]
    float atw = fabsf(tw[0]);
    float tq = ts[b * L + q];

    const float* Qrow = qkv + (size_t)(b * NROWS + q - ROWS0) * NOUT + h * HD;
    qv[wid][lane] = Qrow[lane];
    __syncthreads();

    // scores: lane-parallel over keys
    for (int kk = lane; kk < nk; kk += 64) {
        int k = kmin + kk;
        const float* Krow = qkv + (size_t)(b * NROWS + k - ROWS0) * NOUT + D + h * HD;
        float s = 0.0f;
#pragma unroll
        for (int d4 = 0; d4 < 16; ++d4) {
            float4 kvv = ((const float4*)Krow)[d4];
            s += qv[wid][d4 * 4 + 0] * kvv.x + qv[wid][d4 * 4 + 1] * kvv.y
               + qv[wid][d4 * 4 + 2] * kvv.z + qv[wid][d4 * 4 + 3] * kvv.w;
        }
        float dt = fabsf(tq - ts[b * L + k]);
        sc[wid][kk] = s * 0.125f + logf(expf(-atw * dt) + 1e-8f);
    }
    __syncthreads();

    // softmax (per wave)
    float m = -INFINITY;
    for (int kk = lane; kk < nk; kk += 64) m = fmaxf(m, sc[wid][kk]);
    for (int o = 32; o; o >>= 1) m = fmaxf(m, __shfl_xor(m, o));
    float lsum = 0.0f;
    for (int kk = lane; kk < nk; kk += 64) {
        float p = expf(sc[wid][kk] - m);
        sc[wid][kk] = p;
        lsum += p;
    }
    for (int o = 32; o; o >>= 1) lsum += __shfl_xor(lsum, o);
    __syncthreads();

    // P·V: lane = dim, coalesced V reads
    float inv = 1.0f / lsum;
    float acc = 0.0f;
    const float* Vbase = qkv + (size_t)(b * NROWS + kmin - ROWS0) * NOUT + 2 * D + h * HD + lane;
#pragma unroll 4
    for (int kk = 0; kk < nk; ++kk) {
        acc += sc[wid][kk] * Vbase[(size_t)kk * NOUT];
    }
    *myout = acc * inv;
}

// ---------------- Weighted aggregation over positions ----------------
__global__ __launch_bounds__(256) void agg_kernel(const float* __restrict__ att,
                                                  const float* __restrict__ seq,
                                                  const int* __restrict__ slen,
                                                  float* __restrict__ aggA,
                                                  float* __restrict__ aggS) {
    int b = blockIdx.x;
    int tid = threadIdx.x;
    __shared__ float w[NQ];
    __shared__ float sden;
    int sl = slen[b];
    for (int i = tid; i < NQ; i += 256) {
        int q = QS + i;
        w[i] = (q < sl) ? expf(-0.1f * (float)(L - 1 - q)) : 0.0f;
    }
    __syncthreads();
    if (tid == 0) {
        float s = 0.0f;
        for (int i = 0; i < NQ; ++i) s += w[i];
        sden = 1.0f / (s + 1e-8f);   // matches reference's +1e-8 in pw denominator
    }
    __syncthreads();
    float inv = sden;
    for (int j = tid; j < D; j += 256) {
        float a = 0.0f, ssum = 0.0f;
        for (int i = 0; i < NQ; ++i) {
            float wi = w[i];
            a    += wi * att[((size_t)(b * NQ + i)) * D + j];
            ssum += wi * seq[((size_t)b * L + QS + i) * D + j];
        }
        aggA[b * D + j] = a * inv;
        aggS[b * D + j] = ssum * inv;
    }
}

// ---------------- Final: out[b,d] = aggA[b,:]·Wo[d,:] + bo[d] + aggS[b,d] ----------------
__global__ __launch_bounds__(64) void out_kernel(const float* __restrict__ aggA,
                                                 const float* __restrict__ aggS,
                                                 const float* __restrict__ Wo,
                                                 const float* __restrict__ bo,
                                                 float* __restrict__ out) {
    int bid = blockIdx.x;         // 0..B*D-1
    int b = bid >> 9;
    int d = bid & 511;
    int lane = threadIdx.x;
    const float* wrow = Wo + (size_t)d * D;
    const float* arow = aggA + b * D;
    float acc = 0.0f;
#pragma unroll
    for (int i = 0; i < 8; ++i) {
        int j = lane + 64 * i;
        acc += arow[j] * wrow[j];
    }
    for (int o = 32; o; o >>= 1) acc += __shfl_xor(acc, o);
    if (lane == 0) out[b * D + d] = acc + bo[d] + aggS[b * D + d];
}

extern "C" void kernel_launch(void* const* d_in, const int* in_sizes, int n_in,
                              void* d_out, int out_size, void* d_ws, size_t ws_size,
                              hipStream_t stream) {
    const float* seq   = (const float*)d_in[0];
    const int*   slen  = (const int*)d_in[1];
    const float* ts    = (const float*)d_in[2];
    const float* gamma = (const float*)d_in[3];
    const float* beta  = (const float*)d_in[4];
    const float* Wq    = (const float*)d_in[5];
    const float* Wk    = (const float*)d_in[6];
    const float* Wv    = (const float*)d_in[7];
    const float* Wo    = (const float*)d_in[8];
    const float* bo    = (const float*)d_in[9];
    const float* tw    = (const float*)d_in[10];
    float* out = (float*)d_out;

    float* ws   = (float*)d_ws;
    float* x    = ws;                              // MROWS*D      = 524288 floats
    float* qkv  = x + (size_t)MROWS * D;           // MROWS*NOUT   = 1572864
    float* att  = qkv + (size_t)MROWS * NOUT;      // B*NQ*D       = 393216
    float* aggA = att + (size_t)B * NQ * D;        // B*D
    float* aggS = aggA + B * D;                    // B*D
    // total ~10 MB of d_ws

    ln_kernel<<<MROWS, 64, 0, stream>>>(seq, gamma, beta, x);
    dim3 ggrid(MROWS / BM, NOUT / BN);
    qkv_gemm<<<ggrid, 256, 0, stream>>>(x, Wq, Wk, Wv, qkv);
    attn_kernel<<<B * NQ * 2, 256, 0, stream>>>(qkv, ts, slen, tw, att);
    agg_kernel<<<B, 256, 0, stream>>>(att, seq, slen, aggA, aggS);
    out_kernel<<<B * D, 64, 0, stream>>>(aggA, aggS, Wo, bo, out);
}

// Round 2
// 171.571 us; speedup vs baseline: 1.3528x; 1.3528x over previous
//
#include <hip/hip_runtime.h>
#include <math.h>

// Problem constants
#define B 2
#define L 2048
#define D 512
#define H 8
#define HD 64
#define W2 128            // WINDOW/2
#define NOUT (3*D)        // 1536 (Q|K|V concatenated)

// Truncation: pw[l] ~ exp(-0.1*(2047-l)); seqlen in [1920,2048].
// Queries below QS have relative weight <= e^-38 -> negligible vs 1.6e-2 threshold.
#define QS 1664
#define NQ (L - QS)       // 384 queries per batch
#define ROWS0 (QS - W2)   // 1536: lowest key row needed
#define NROWS (L - ROWS0) // 512 LN/QKV rows per batch
#define MROWS (B * NROWS) // 1024

#define TQ 4              // queries per attention block
#define NQT (NQ / TQ)     // 96 query tiles

// ---------------- LayerNorm: one wave per row ----------------
__global__ __launch_bounds__(64) void ln_kernel(const float* __restrict__ seq,
                                                const float* __restrict__ gamma,
                                                const float* __restrict__ beta,
                                                float* __restrict__ x) {
    int row = blockIdx.x;           // 0..MROWS-1
    int b = row / NROWS;
    int l = ROWS0 + (row - b * NROWS);
    const float* src = seq + ((size_t)b * L + l) * D;
    int lane = threadIdx.x;
    float4 v0 = ((const float4*)src)[lane];
    float4 v1 = ((const float4*)src)[lane + 64];
    float s  = v0.x + v0.y + v0.z + v0.w + v1.x + v1.y + v1.z + v1.w;
    float sq = v0.x*v0.x + v0.y*v0.y + v0.z*v0.z + v0.w*v0.w
             + v1.x*v1.x + v1.y*v1.y + v1.z*v1.z + v1.w*v1.w;
    for (int o = 32; o; o >>= 1) { s += __shfl_xor(s, o); sq += __shfl_xor(sq, o); }
    float mu = s * (1.0f / D);
    float var = sq * (1.0f / D) - mu * mu;
    float rstd = rsqrtf(var + 1e-5f);
    float4 g0 = ((const float4*)gamma)[lane];
    float4 g1 = ((const float4*)gamma)[lane + 64];
    float4 b0 = ((const float4*)beta)[lane];
    float4 b1 = ((const float4*)beta)[lane + 64];
    float4 o0, o1;
    o0.x = (v0.x - mu) * rstd * g0.x + b0.x;
    o0.y = (v0.y - mu) * rstd * g0.y + b0.y;
    o0.z = (v0.z - mu) * rstd * g0.z + b0.z;
    o0.w = (v0.w - mu) * rstd * g0.w + b0.w;
    o1.x = (v1.x - mu) * rstd * g1.x + b1.x;
    o1.y = (v1.y - mu) * rstd * g1.y + b1.y;
    o1.z = (v1.z - mu) * rstd * g1.z + b1.z;
    o1.w = (v1.w - mu) * rstd * g1.w + b1.w;
    float* dst = x + (size_t)row * D;
    ((float4*)dst)[lane] = o0;
    ((float4*)dst)[lane + 64] = o1;
}

// ---------------- QKV GEMM: C[m, o] = sum_d x[m,d] * W[o,d] ----------------
#define BM 64
#define BN 64
#define BK 16
#define LDP (BM + 4)

__global__ __launch_bounds__(256) void qkv_gemm(const float* __restrict__ x,
                                                const float* __restrict__ Wq,
                                                const float* __restrict__ Wk,
                                                const float* __restrict__ Wv,
                                                float* __restrict__ qkv) {
    __shared__ float As[BK][LDP];
    __shared__ float Bs[BK][LDP];
    int tid = threadIdx.x;
    int m0 = blockIdx.x * BM;
    int n0 = blockIdx.y * BN;
    const float* Wsel = (n0 < D) ? Wq : (n0 < 2 * D ? Wk : Wv);
    int ob = n0 & (D - 1);
    int lr = tid >> 2;
    int lc = (tid & 3) * 4;
    const float* aptr = x + (size_t)(m0 + lr) * D + lc;
    const float* bptr = Wsel + (size_t)(ob + lr) * D + lc;
    int ty = tid >> 4, tx = tid & 15;
    float acc[4][4] = {};
    for (int kt = 0; kt < D; kt += BK) {
        float4 av = *(const float4*)(aptr + kt);
        float4 bv = *(const float4*)(bptr + kt);
        __syncthreads();
        As[lc + 0][lr] = av.x; As[lc + 1][lr] = av.y;
        As[lc + 2][lr] = av.z; As[lc + 3][lr] = av.w;
        Bs[lc + 0][lr] = bv.x; Bs[lc + 1][lr] = bv.y;
        Bs[lc + 2][lr] = bv.z; Bs[lc + 3][lr] = bv.w;
        __syncthreads();
#pragma unroll
        for (int k = 0; k < BK; ++k) {
            float4 a = *(const float4*)&As[k][ty * 4];
            float4 bb = *(const float4*)&Bs[k][tx * 4];
            acc[0][0] += a.x * bb.x; acc[0][1] += a.x * bb.y; acc[0][2] += a.x * bb.z; acc[0][3] += a.x * bb.w;
            acc[1][0] += a.y * bb.x; acc[1][1] += a.y * bb.y; acc[1][2] += a.y * bb.z; acc[1][3] += a.y * bb.w;
            acc[2][0] += a.z * bb.x; acc[2][1] += a.z * bb.y; acc[2][2] += a.z * bb.z; acc[2][3] += a.z * bb.w;
            acc[3][0] += a.w * bb.x; acc[3][1] += a.w * bb.y; acc[3][2] += a.w * bb.z; acc[3][3] += a.w * bb.w;
        }
    }
#pragma unroll
    for (int i = 0; i < 4; ++i) {
        float4 o = make_float4(acc[i][0], acc[i][1], acc[i][2], acc[i][3]);
        *(float4*)(qkv + (size_t)(m0 + ty * 4 + i) * NOUT + n0 + tx * 4) = o;
    }
}

// ---------------- Attention: block = (b, q-tile of 4, head); 4 waves split keys ----------------
// Flash-style: each wave computes partial (m, l, acc) over its key chunk, then merge.
__global__ __launch_bounds__(256) void attn_kernel(const float* __restrict__ qkv,
                                                   const float* __restrict__ ts,
                                                   const int* __restrict__ slen,
                                                   const float* __restrict__ tw,
                                                   float* __restrict__ att) {
    int bid = blockIdx.x;
    int b = bid / (NQT * H);
    int rem = bid - b * (NQT * H);
    int qt = rem / H;
    int h = rem - qt * H;
    int wid = threadIdx.x >> 6;
    int lane = threadIdx.x & 63;
    int q0 = QS + qt * TQ;
    int sl = slen[b];
    int kmin = q0 - W2;
    int kmax = min(q0 + TQ - 1 + W2, sl - 1);
    int nk = kmax - kmin + 1;          // in [5, 260]
    int chunk = (nk + 3) >> 2;         // <= 65
    int start = wid * chunk;
    int end = min(start + chunk, nk);
    int cnt = max(end - start, 0);

    __shared__ __attribute__((aligned(16))) float qv[TQ][HD];
    __shared__ __attribute__((aligned(16))) float p[4][66][TQ];
    __shared__ __attribute__((aligned(16))) float pacc[4][TQ][HD];
    __shared__ float mlm[4][TQ];
    __shared__ float mll[4][TQ];
    __shared__ float tqs[TQ];

    // load Q tile: wave t loads query t's 64 dims (coalesced)
    {
        int row = b * NROWS + (q0 + wid - ROWS0);
        qv[wid][lane] = qkv[(size_t)row * NOUT + h * HD + lane];
        if (lane == 0) tqs[wid] = ts[b * L + q0 + wid];
    }
    __syncthreads();

    float atw = fabsf(tw[0]);

    // ---- scores: each wave handles its chunk; lane = key; <=2 iterations ----
    float m[TQ] = {-INFINITY, -INFINITY, -INFINITY, -INFINITY};
    float sreg[2][TQ];
#pragma unroll
    for (int it = 0; it < 2; ++it) {
        int kk = start + it * 64 + lane;
        bool act = (kk < end);
        float s[TQ] = {0.f, 0.f, 0.f, 0.f};
        if (act) {
            int k = kmin + kk;
            const float* Krow = qkv + (size_t)(b * NROWS + k - ROWS0) * NOUT + D + h * HD;
#pragma unroll
            for (int d4 = 0; d4 < 16; ++d4) {
                float4 kv = ((const float4*)Krow)[d4];
#pragma unroll
                for (int t = 0; t < TQ; ++t) {
                    float4 qq = *(const float4*)&qv[t][d4 * 4];
                    s[t] += qq.x * kv.x + qq.y * kv.y + qq.z * kv.z + qq.w * kv.w;
                }
            }
            float tk = ts[b * L + k];
#pragma unroll
            for (int t = 0; t < TQ; ++t) {
                float dt = fabsf(tqs[t] - tk);
                float bias = logf(expf(-atw * dt) + 1e-8f);
                int qa = q0 + t;
                bool valid = (k >= qa - W2) && (k <= qa + W2);
                s[t] = valid ? (s[t] * 0.125f + bias) : -INFINITY;
            }
        } else {
#pragma unroll
            for (int t = 0; t < TQ; ++t) s[t] = -INFINITY;
        }
#pragma unroll
        for (int t = 0; t < TQ; ++t) { sreg[it][t] = s[t]; m[t] = fmaxf(m[t], s[t]); }
    }
#pragma unroll
    for (int t = 0; t < TQ; ++t)
        for (int o = 32; o; o >>= 1) m[t] = fmaxf(m[t], __shfl_xor(m[t], o));

    float l[TQ] = {0.f, 0.f, 0.f, 0.f};
#pragma unroll
    for (int it = 0; it < 2; ++it) {
        int kk = start + it * 64 + lane;
        bool act = (kk < end);
        float pv[TQ];
#pragma unroll
        for (int t = 0; t < TQ; ++t) {
            float pp = (m[t] > -INFINITY) ? expf(sreg[it][t] - m[t]) : 0.0f;
            pv[t] = pp;
            l[t] += act ? pp : 0.0f;
        }
        if (act) {
            *(float4*)&p[wid][kk - start][0] = make_float4(pv[0], pv[1], pv[2], pv[3]);
        }
    }
#pragma unroll
    for (int t = 0; t < TQ; ++t)
        for (int o = 32; o; o >>= 1) l[t] += __shfl_xor(l[t], o);
    if (lane == 0) {
#pragma unroll
        for (int t = 0; t < TQ; ++t) { mlm[wid][t] = m[t]; mll[wid][t] = l[t]; }
    }

    // ---- P·V over own chunk: lane = dim, coalesced V reads, 4-acc ILP ----
    float acc[TQ] = {0.f, 0.f, 0.f, 0.f};
    const float* Vbase = qkv + (size_t)(b * NROWS + kmin + start - ROWS0) * NOUT + 2 * D + h * HD + lane;
#pragma unroll 4
    for (int kl = 0; kl < cnt; ++kl) {
        float v = Vbase[(size_t)kl * NOUT];
        float4 pp = *(const float4*)&p[wid][kl][0];
        acc[0] += pp.x * v; acc[1] += pp.y * v; acc[2] += pp.z * v; acc[3] += pp.w * v;
    }
#pragma unroll
    for (int t = 0; t < TQ; ++t) pacc[wid][t][lane] = acc[t];
    __syncthreads();

    // ---- merge partials: wave = query, lane = dim ----
    {
        int t = wid;
        float m0 = mlm[0][t], m1 = mlm[1][t], m2 = mlm[2][t], m3 = mlm[3][t];
        float M = fmaxf(fmaxf(m0, m1), fmaxf(m2, m3));
        float e0 = expf(m0 - M), e1 = expf(m1 - M), e2 = expf(m2 - M), e3 = expf(m3 - M);
        float Lsum = e0 * mll[0][t] + e1 * mll[1][t] + e2 * mll[2][t] + e3 * mll[3][t];
        float o = e0 * pacc[0][t][lane] + e1 * pacc[1][t][lane]
                + e2 * pacc[2][t][lane] + e3 * pacc[3][t][lane];
        att[((size_t)(b * NQ + qt * TQ + t)) * D + h * HD + lane] = o / Lsum;
    }
}

// ---------------- Weighted aggregation: grid (B*8), block = 4 waves, wave-split i ----------------
__global__ __launch_bounds__(256) void agg_kernel(const float* __restrict__ att,
                                                  const float* __restrict__ seq,
                                                  const int* __restrict__ slen,
                                                  float* __restrict__ aggA,
                                                  float* __restrict__ aggS) {
    int b = blockIdx.x >> 3;
    int ctile = blockIdx.x & 7;
    int tid = threadIdx.x;
    int wid = tid >> 6, lane = tid & 63;
    int col = ctile * 64 + lane;
    int sl = slen[b];
    int nv = min(NQ, sl - QS);       // valid query count (>= 256)

    __shared__ float w[NQ];
    __shared__ float redA[4][64];
    __shared__ float redS[4][64];
    __shared__ float dsum;

    for (int i = tid; i < NQ; i += 256)
        w[i] = (i < nv) ? expf(-0.1f * (float)(NQ - 1 - i)) : 0.0f;
    __syncthreads();

    float dpart = 0.f;
    for (int i = tid; i < NQ; i += 256) dpart += w[i];
    for (int o = 32; o; o >>= 1) dpart += __shfl_xor(dpart, o);
    if (lane == 0) redA[wid][0] = dpart;
    __syncthreads();
    if (tid == 0) dsum = 1.0f / (redA[0][0] + redA[1][0] + redA[2][0] + redA[3][0] + 1e-8f);
    __syncthreads();

    float a = 0.f, s2 = 0.f;
    int i0 = wid * 96, i1 = min(i0 + 96, nv);
    for (int i = i0; i < i1; ++i) {
        float wi = w[i];
        a  += wi * att[((size_t)(b * NQ + i)) * D + col];
        s2 += wi * seq[((size_t)(b * L + QS + i)) * D + col];
    }
    redA[wid][lane] = a; redS[wid][lane] = s2;
    __syncthreads();
    if (wid == 0) {
        float A = redA[0][lane] + redA[1][lane] + redA[2][lane] + redA[3][lane];
        float S = redS[0][lane] + redS[1][lane] + redS[2][lane] + redS[3][lane];
        aggA[b * D + col] = A * dsum;
        aggS[b * D + col] = S * dsum;
    }
}

// ---------------- Final: out[b,d] = aggA[b,:]·Wo[d,:] + bo[d] + aggS[b,d] ----------------
__global__ __launch_bounds__(64) void out_kernel(const float* __restrict__ aggA,
                                                 const float* __restrict__ aggS,
                                                 const float* __restrict__ Wo,
                                                 const float* __restrict__ bo,
                                                 float* __restrict__ out) {
    int bid = blockIdx.x;
    int b = bid >> 9;
    int d = bid & 511;
    int lane = threadIdx.x;
    const float* wrow = Wo + (size_t)d * D;
    const float* arow = aggA + b * D;
    float acc = 0.0f;
#pragma unroll
    for (int i = 0; i < 8; ++i) {
        int j = lane + 64 * i;
        acc += arow[j] * wrow[j];
    }
    for (int o = 32; o; o >>= 1) acc += __shfl_xor(acc, o);
    if (lane == 0) out[b * D + d] = acc + bo[d] + aggS[b * D + d];
}

extern "C" void kernel_launch(void* const* d_in, const int* in_sizes, int n_in,
                              void* d_out, int out_size, void* d_ws, size_t ws_size,
                              hipStream_t stream) {
    const float* seq   = (const float*)d_in[0];
    const int*   slen  = (const int*)d_in[1];
    const float* ts    = (const float*)d_in[2];
    const float* gamma = (const float*)d_in[3];
    const float* beta  = (const float*)d_in[4];
    const float* Wq    = (const float*)d_in[5];
    const float* Wk    = (const float*)d_in[6];
    const float* Wv    = (const float*)d_in[7];
    const float* Wo    = (const float*)d_in[8];
    const float* bo    = (const float*)d_in[9];
    const float* tw    = (const float*)d_in[10];
    float* out = (float*)d_out;

    float* ws   = (float*)d_ws;
    float* x    = ws;
    float* qkv  = x + (size_t)MROWS * D;
    float* att  = qkv + (size_t)MROWS * NOUT;
    float* aggA = att + (size_t)B * NQ * D;
    float* aggS = aggA + B * D;

    ln_kernel<<<MROWS, 64, 0, stream>>>(seq, gamma, beta, x);
    dim3 ggrid(MROWS / BM, NOUT / BN);
    qkv_gemm<<<ggrid, 256, 0, stream>>>(x, Wq, Wk, Wv, qkv);
    attn_kernel<<<B * NQT * H, 256, 0, stream>>>(qkv, ts, slen, tw, att);
    agg_kernel<<<B * 8, 256, 0, stream>>>(att, seq, slen, aggA, aggS);
    out_kernel<<<B * D, 64, 0, stream>>>(aggA, aggS, Wo, bo, out);
}

// Round 3
// 159.378 us; speedup vs baseline: 1.4563x; 1.0765x over previous
//
#include <hip/hip_runtime.h>
#include <math.h>

// Problem constants
#define B 2
#define L 2048
#define D 512
#define H 8
#define HD 64
#define W2 128            // WINDOW/2
#define NOUT (3*D)        // 1536 (Q|K|V concatenated)

// Truncation: pw[l] ~ exp(-0.1*(2047-l)); seqlen in [1920,2048].
// Queries below QS have relative weight <= e^-38 -> negligible vs 1.6e-2 threshold.
#define QS 1664
#define NQ (L - QS)       // 384 queries per batch
#define ROWS0 (QS - W2)   // 1536: lowest key row needed
#define NROWS (L - ROWS0) // 512 LN/QKV rows per batch
#define MROWS (B * NROWS) // 1024

#define TQ 4              // queries per attention block
#define NQT (NQ / TQ)     // 96 query tiles

typedef __bf16 bf16_t;
typedef __attribute__((ext_vector_type(4))) __bf16 bf16x4;
typedef __attribute__((ext_vector_type(8))) __bf16 bf16x8;
typedef __attribute__((ext_vector_type(4))) float f32x4;

// ---------------- LayerNorm: one wave per row; emits bf16 for the MFMA GEMM ----------------
__global__ __launch_bounds__(64) void ln_kernel(const float* __restrict__ seq,
                                                const float* __restrict__ gamma,
                                                const float* __restrict__ beta,
                                                bf16_t* __restrict__ xb) {
    int row = blockIdx.x;           // 0..MROWS-1
    int b = row / NROWS;
    int l = ROWS0 + (row - b * NROWS);
    const float* src = seq + ((size_t)b * L + l) * D;
    int lane = threadIdx.x;
    float4 v0 = ((const float4*)src)[lane];
    float4 v1 = ((const float4*)src)[lane + 64];
    float s  = v0.x + v0.y + v0.z + v0.w + v1.x + v1.y + v1.z + v1.w;
    float sq = v0.x*v0.x + v0.y*v0.y + v0.z*v0.z + v0.w*v0.w
             + v1.x*v1.x + v1.y*v1.y + v1.z*v1.z + v1.w*v1.w;
    for (int o = 32; o; o >>= 1) { s += __shfl_xor(s, o); sq += __shfl_xor(sq, o); }
    float mu = s * (1.0f / D);
    float var = sq * (1.0f / D) - mu * mu;
    float rstd = rsqrtf(var + 1e-5f);
    float4 g0 = ((const float4*)gamma)[lane];
    float4 g1 = ((const float4*)gamma)[lane + 64];
    float4 b0 = ((const float4*)beta)[lane];
    float4 b1 = ((const float4*)beta)[lane + 64];
    bf16x4 c0, c1;
    c0[0] = (bf16_t)((v0.x - mu) * rstd * g0.x + b0.x);
    c0[1] = (bf16_t)((v0.y - mu) * rstd * g0.y + b0.y);
    c0[2] = (bf16_t)((v0.z - mu) * rstd * g0.z + b0.z);
    c0[3] = (bf16_t)((v0.w - mu) * rstd * g0.w + b0.w);
    c1[0] = (bf16_t)((v1.x - mu) * rstd * g1.x + b1.x);
    c1[1] = (bf16_t)((v1.y - mu) * rstd * g1.y + b1.y);
    c1[2] = (bf16_t)((v1.z - mu) * rstd * g1.z + b1.z);
    c1[3] = (bf16_t)((v1.w - mu) * rstd * g1.w + b1.w);
    bf16x4* dst = (bf16x4*)(xb + (size_t)row * D);
    dst[lane] = c0;
    dst[lane + 64] = c1;
}

// ---------------- Weight cast: Wq|Wk|Wv (fp32) -> wb (bf16, 1536x512, flat concat) ----------------
__global__ __launch_bounds__(256) void cvt_w(const float* __restrict__ Wq,
                                             const float* __restrict__ Wk,
                                             const float* __restrict__ Wv,
                                             bf16_t* __restrict__ wb) {
    int idx = blockIdx.x * 256 + threadIdx.x;   // over 3*512*512/4 = 196608 float4s
    const float* src = (idx < 65536) ? Wq : (idx < 131072 ? Wk : Wv);
    int off = idx & 65535;
    float4 v = ((const float4*)src)[off];
    bf16x4 o;
    o[0] = (bf16_t)v.x; o[1] = (bf16_t)v.y; o[2] = (bf16_t)v.z; o[3] = (bf16_t)v.w;
    ((bf16x4*)wb)[idx] = o;
}

// ---------------- QKV GEMM via MFMA: qkv[m,n] = sum_k xb[m,k] * wb[n,k] ----------------
// M=1024, N=1536, K=512. Block = 4 waves; block tile 64x64; wave tile 32x32 (2x2 MFMA 16x16x32).
// No LDS: both operands are K-contiguous, lanes load 16B fragments straight from global (L2-hot).
__global__ __launch_bounds__(256) void qkv_gemm(const bf16_t* __restrict__ xb,
                                                const bf16_t* __restrict__ wb,
                                                float* __restrict__ qkv) {
    int m0 = blockIdx.x * 64, n0 = blockIdx.y * 64;
    int wid = threadIdx.x >> 6, lane = threadIdx.x & 63;
    int mw = m0 + (wid >> 1) * 32;
    int nw = n0 + (wid & 1) * 32;
    int mr = lane & 15, quad = lane >> 4;
    f32x4 acc00 = {}, acc01 = {}, acc10 = {}, acc11 = {};
    const bf16_t* aptr = xb + (size_t)(mw + mr) * D + quad * 8;
    const bf16_t* bptr = wb + (size_t)(nw + mr) * D + quad * 8;
#pragma unroll 4
    for (int k = 0; k < D; k += 32) {
        bf16x8 a0 = *(const bf16x8*)(aptr + k);
        bf16x8 a1 = *(const bf16x8*)(aptr + 16 * D + k);
        bf16x8 b0 = *(const bf16x8*)(bptr + k);
        bf16x8 b1 = *(const bf16x8*)(bptr + 16 * D + k);
        acc00 = __builtin_amdgcn_mfma_f32_16x16x32_bf16(a0, b0, acc00, 0, 0, 0);
        acc01 = __builtin_amdgcn_mfma_f32_16x16x32_bf16(a0, b1, acc01, 0, 0, 0);
        acc10 = __builtin_amdgcn_mfma_f32_16x16x32_bf16(a1, b0, acc10, 0, 0, 0);
        acc11 = __builtin_amdgcn_mfma_f32_16x16x32_bf16(a1, b1, acc11, 0, 0, 0);
    }
    // D[m][n]: m = mi*16 + quad*4 + r, n = nj*16 + mr
    float* base = qkv + (size_t)(mw + quad * 4) * NOUT + nw + mr;
#pragma unroll
    for (int r = 0; r < 4; ++r) {
        base[(size_t)r * NOUT +  0] = acc00[r];
        base[(size_t)r * NOUT + 16] = acc01[r];
        base[(size_t)(16 + r) * NOUT +  0] = acc10[r];
        base[(size_t)(16 + r) * NOUT + 16] = acc11[r];
    }
}

// ---------------- Attention: block = (b, q-tile of 4, head); 4 waves split keys ----------------
__global__ __launch_bounds__(256) void attn_kernel(const float* __restrict__ qkv,
                                                   const float* __restrict__ ts,
                                                   const int* __restrict__ slen,
                                                   const float* __restrict__ tw,
                                                   float* __restrict__ att) {
    int bid = blockIdx.x;
    int b = bid / (NQT * H);
    int rem = bid - b * (NQT * H);
    int qt = rem / H;
    int h = rem - qt * H;
    int wid = threadIdx.x >> 6;
    int lane = threadIdx.x & 63;
    int q0 = QS + qt * TQ;
    int sl = slen[b];
    int kmin = q0 - W2;
    int kmax = min(q0 + TQ - 1 + W2, sl - 1);
    int nk = kmax - kmin + 1;          // in [5, 260]
    int chunk = (nk + 3) >> 2;         // <= 65
    int start = wid * chunk;
    int end = min(start + chunk, nk);
    int cnt = max(end - start, 0);

    __shared__ __attribute__((aligned(16))) float qv[TQ][HD];
    __shared__ __attribute__((aligned(16))) float p[4][66][TQ];
    __shared__ __attribute__((aligned(16))) float pacc[4][TQ][HD];
    __shared__ float mlm[4][TQ];
    __shared__ float mll[4][TQ];
    __shared__ float tqs[TQ];

    {
        int row = b * NROWS + (q0 + wid - ROWS0);
        qv[wid][lane] = qkv[(size_t)row * NOUT + h * HD + lane];
        if (lane == 0) tqs[wid] = ts[b * L + q0 + wid];
    }
    __syncthreads();

    float atw = fabsf(tw[0]);

    float m[TQ] = {-INFINITY, -INFINITY, -INFINITY, -INFINITY};
    float sreg[2][TQ];
#pragma unroll
    for (int it = 0; it < 2; ++it) {
        int kk = start + it * 64 + lane;
        bool act = (kk < end);
        float s[TQ] = {0.f, 0.f, 0.f, 0.f};
        if (act) {
            int k = kmin + kk;
            const float* Krow = qkv + (size_t)(b * NROWS + k - ROWS0) * NOUT + D + h * HD;
#pragma unroll
            for (int d4 = 0; d4 < 16; ++d4) {
                float4 kv = ((const float4*)Krow)[d4];
#pragma unroll
                for (int t = 0; t < TQ; ++t) {
                    float4 qq = *(const float4*)&qv[t][d4 * 4];
                    s[t] += qq.x * kv.x + qq.y * kv.y + qq.z * kv.z + qq.w * kv.w;
                }
            }
            float tk = ts[b * L + k];
#pragma unroll
            for (int t = 0; t < TQ; ++t) {
                float dt = fabsf(tqs[t] - tk);
                float bias = logf(expf(-atw * dt) + 1e-8f);
                int qa = q0 + t;
                bool valid = (k >= qa - W2) && (k <= qa + W2);
                s[t] = valid ? (s[t] * 0.125f + bias) : -INFINITY;
            }
        } else {
#pragma unroll
            for (int t = 0; t < TQ; ++t) s[t] = -INFINITY;
        }
#pragma unroll
        for (int t = 0; t < TQ; ++t) { sreg[it][t] = s[t]; m[t] = fmaxf(m[t], s[t]); }
    }
#pragma unroll
    for (int t = 0; t < TQ; ++t)
        for (int o = 32; o; o >>= 1) m[t] = fmaxf(m[t], __shfl_xor(m[t], o));

    float l[TQ] = {0.f, 0.f, 0.f, 0.f};
#pragma unroll
    for (int it = 0; it < 2; ++it) {
        int kk = start + it * 64 + lane;
        bool act = (kk < end);
        float pv[TQ];
#pragma unroll
        for (int t = 0; t < TQ; ++t) {
            float pp = (m[t] > -INFINITY) ? expf(sreg[it][t] - m[t]) : 0.0f;
            pv[t] = pp;
            l[t] += act ? pp : 0.0f;
        }
        if (act) {
            *(float4*)&p[wid][kk - start][0] = make_float4(pv[0], pv[1], pv[2], pv[3]);
        }
    }
#pragma unroll
    for (int t = 0; t < TQ; ++t)
        for (int o = 32; o; o >>= 1) l[t] += __shfl_xor(l[t], o);
    if (lane == 0) {
#pragma unroll
        for (int t = 0; t < TQ; ++t) { mlm[wid][t] = m[t]; mll[wid][t] = l[t]; }
    }

    float acc[TQ] = {0.f, 0.f, 0.f, 0.f};
    const float* Vbase = qkv + (size_t)(b * NROWS + kmin + start - ROWS0) * NOUT + 2 * D + h * HD + lane;
#pragma unroll 4
    for (int kl = 0; kl < cnt; ++kl) {
        float v = Vbase[(size_t)kl * NOUT];
        float4 pp = *(const float4*)&p[wid][kl][0];
        acc[0] += pp.x * v; acc[1] += pp.y * v; acc[2] += pp.z * v; acc[3] += pp.w * v;
    }
#pragma unroll
    for (int t = 0; t < TQ; ++t) pacc[wid][t][lane] = acc[t];
    __syncthreads();

    {
        int t = wid;
        float m0 = mlm[0][t], m1 = mlm[1][t], m2 = mlm[2][t], m3 = mlm[3][t];
        float M = fmaxf(fmaxf(m0, m1), fmaxf(m2, m3));
        float e0 = expf(m0 - M), e1 = expf(m1 - M), e2 = expf(m2 - M), e3 = expf(m3 - M);
        float Lsum = e0 * mll[0][t] + e1 * mll[1][t] + e2 * mll[2][t] + e3 * mll[3][t];
        float o = e0 * pacc[0][t][lane] + e1 * pacc[1][t][lane]
                + e2 * pacc[2][t][lane] + e3 * pacc[3][t][lane];
        att[((size_t)(b * NQ + qt * TQ + t)) * D + h * HD + lane] = o / Lsum;
    }
}

// ---------------- Weighted aggregation: grid (B*8), block = 4 waves, wave-split i ----------------
__global__ __launch_bounds__(256) void agg_kernel(const float* __restrict__ att,
                                                  const float* __restrict__ seq,
                                                  const int* __restrict__ slen,
                                                  float* __restrict__ aggA,
                                                  float* __restrict__ aggS) {
    int b = blockIdx.x >> 3;
    int ctile = blockIdx.x & 7;
    int tid = threadIdx.x;
    int wid = tid >> 6, lane = tid & 63;
    int col = ctile * 64 + lane;
    int sl = slen[b];
    int nv = min(NQ, sl - QS);       // valid query count (>= 256)

    __shared__ float w[NQ];
    __shared__ float redA[4][64];
    __shared__ float redS[4][64];
    __shared__ float dsum;

    for (int i = tid; i < NQ; i += 256)
        w[i] = (i < nv) ? expf(-0.1f * (float)(NQ - 1 - i)) : 0.0f;
    __syncthreads();

    float dpart = 0.f;
    for (int i = tid; i < NQ; i += 256) dpart += w[i];
    for (int o = 32; o; o >>= 1) dpart += __shfl_xor(dpart, o);
    if (lane == 0) redA[wid][0] = dpart;
    __syncthreads();
    if (tid == 0) dsum = 1.0f / (redA[0][0] + redA[1][0] + redA[2][0] + redA[3][0] + 1e-8f);
    __syncthreads();

    float a = 0.f, s2 = 0.f;
    int i0 = wid * 96, i1 = min(i0 + 96, nv);
    for (int i = i0; i < i1; ++i) {
        float wi = w[i];
        a  += wi * att[((size_t)(b * NQ + i)) * D + col];
        s2 += wi * seq[((size_t)(b * L + QS + i)) * D + col];
    }
    redA[wid][lane] = a; redS[wid][lane] = s2;
    __syncthreads();
    if (wid == 0) {
        float A = redA[0][lane] + redA[1][lane] + redA[2][lane] + redA[3][lane];
        float S = redS[0][lane] + redS[1][lane] + redS[2][lane] + redS[3][lane];
        aggA[b * D + col] = A * dsum;
        aggS[b * D + col] = S * dsum;
    }
}

// ---------------- Final: out[b,d] = aggA[b,:]·Wo[d,:] + bo[d] + aggS[b,d] ----------------
__global__ __launch_bounds__(64) void out_kernel(const float* __restrict__ aggA,
                                                 const float* __restrict__ aggS,
                                                 const float* __restrict__ Wo,
                                                 const float* __restrict__ bo,
                                                 float* __restrict__ out) {
    int bid = blockIdx.x;
    int b = bid >> 9;
    int d = bid & 511;
    int lane = threadIdx.x;
    const float* wrow = Wo + (size_t)d * D;
    const float* arow = aggA + b * D;
    float acc = 0.0f;
#pragma unroll
    for (int i = 0; i < 8; ++i) {
        int j = lane + 64 * i;
        acc += arow[j] * wrow[j];
    }
    for (int o = 32; o; o >>= 1) acc += __shfl_xor(acc, o);
    if (lane == 0) out[b * D + d] = acc + bo[d] + aggS[b * D + d];
}

extern "C" void kernel_launch(void* const* d_in, const int* in_sizes, int n_in,
                              void* d_out, int out_size, void* d_ws, size_t ws_size,
                              hipStream_t stream) {
    const float* seq   = (const float*)d_in[0];
    const int*   slen  = (const int*)d_in[1];
    const float* ts    = (const float*)d_in[2];
    const float* gamma = (const float*)d_in[3];
    const float* beta  = (const float*)d_in[4];
    const float* Wq    = (const float*)d_in[5];
    const float* Wk    = (const float*)d_in[6];
    const float* Wv    = (const float*)d_in[7];
    const float* Wo    = (const float*)d_in[8];
    const float* bo    = (const float*)d_in[9];
    const float* tw    = (const float*)d_in[10];
    float* out = (float*)d_out;

    float* ws   = (float*)d_ws;
    float* qkv  = ws;                              // MROWS*NOUT   = 1572864 floats
    float* att  = qkv + (size_t)MROWS * NOUT;      // B*NQ*D       = 393216
    float* aggA = att + (size_t)B * NQ * D;        // B*D
    float* aggS = aggA + B * D;                    // B*D
    bf16_t* xb  = (bf16_t*)(aggS + B * D);         // MROWS*D bf16 = 1 MB
    bf16_t* wb  = xb + (size_t)MROWS * D;          // NOUT*D bf16  = 1.5 MB

    ln_kernel<<<MROWS, 64, 0, stream>>>(seq, gamma, beta, xb);
    cvt_w<<<768, 256, 0, stream>>>(Wq, Wk, Wv, wb);
    dim3 ggrid(MROWS / 64, NOUT / 64);
    qkv_gemm<<<ggrid, 256, 0, stream>>>(xb, wb, qkv);
    attn_kernel<<<B * NQT * H, 256, 0, stream>>>(qkv, ts, slen, tw, att);
    agg_kernel<<<B * 8, 256, 0, stream>>>(att, seq, slen, aggA, aggS);
    out_kernel<<<B * D, 64, 0, stream>>>(aggA, aggS, Wo, bo, out);
}

// Round 4
// 130.200 us; speedup vs baseline: 1.7827x; 1.2241x over previous
//
#include <hip/hip_runtime.h>
#include <math.h>

// Problem constants
#define B 2
#define L 2048
#define D 512
#define H 8
#define HD 64
#define W2 128            // WINDOW/2
#define NOUT (3*D)        // 1536 (Q|K|V concatenated)

// Truncation: pw[l] ~ exp(-0.1*(2047-l)); seqlen in [1920,2048].
// Omitted-query relative weight <= e^-12.8 ~ 2.7e-6 -> negligible vs 1.6e-2 threshold.
#define QS 1792
#define NQ (L - QS)       // 256 queries per batch
#define ROWS0 (QS - W2)   // 1664: lowest key row needed
#define NROWS (L - ROWS0) // 384 LN/QKV rows per batch
#define MROWS (B * NROWS) // 768

#define TQ 4              // queries per attention block
#define NQT (NQ / TQ)     // 64 query tiles

typedef __bf16 bf16_t;
typedef __attribute__((ext_vector_type(4))) __bf16 bf16x4;
typedef __attribute__((ext_vector_type(8))) __bf16 bf16x8;
typedef __attribute__((ext_vector_type(4))) float f32x4;

// prep grid layout
#define PREP_LN_BLOCKS (MROWS / 4)          // 192: 4 rows/block (wave per row)
#define PREP_CVT_BLOCKS 768                  // 196608 float4s / 256
#define PREP_AGGS_BLOCKS 16                  // B * 8 column tiles
#define PREP_GRID (PREP_LN_BLOCKS + PREP_CVT_BLOCKS + PREP_AGGS_BLOCKS + 1)

// ---------------- prep: LN(bf16 out) + weight cast + seq aggregation + aggA zero ----------------
__global__ __launch_bounds__(256) void prep_kernel(const float* __restrict__ seq,
                                                   const float* __restrict__ gamma,
                                                   const float* __restrict__ beta,
                                                   const float* __restrict__ Wq,
                                                   const float* __restrict__ Wk,
                                                   const float* __restrict__ Wv,
                                                   const int* __restrict__ slen,
                                                   bf16_t* __restrict__ xb,
                                                   bf16_t* __restrict__ wb,
                                                   float* __restrict__ aggA,
                                                   float* __restrict__ aggS) {
    int blk = blockIdx.x;
    int tid = threadIdx.x;
    int wid = tid >> 6, lane = tid & 63;

    if (blk < PREP_LN_BLOCKS) {
        // ---- LayerNorm: wave per row ----
        int row = blk * 4 + wid;
        int b = row / NROWS;
        int l = ROWS0 + (row - b * NROWS);
        const float* src = seq + ((size_t)b * L + l) * D;
        float4 v0 = ((const float4*)src)[lane];
        float4 v1 = ((const float4*)src)[lane + 64];
        float s  = v0.x + v0.y + v0.z + v0.w + v1.x + v1.y + v1.z + v1.w;
        float sq = v0.x*v0.x + v0.y*v0.y + v0.z*v0.z + v0.w*v0.w
                 + v1.x*v1.x + v1.y*v1.y + v1.z*v1.z + v1.w*v1.w;
        for (int o = 32; o; o >>= 1) { s += __shfl_xor(s, o); sq += __shfl_xor(sq, o); }
        float mu = s * (1.0f / D);
        float var = sq * (1.0f / D) - mu * mu;
        float rstd = rsqrtf(var + 1e-5f);
        float4 g0 = ((const float4*)gamma)[lane];
        float4 g1 = ((const float4*)gamma)[lane + 64];
        float4 b0 = ((const float4*)beta)[lane];
        float4 b1 = ((const float4*)beta)[lane + 64];
        bf16x4 c0, c1;
        c0[0] = (bf16_t)((v0.x - mu) * rstd * g0.x + b0.x);
        c0[1] = (bf16_t)((v0.y - mu) * rstd * g0.y + b0.y);
        c0[2] = (bf16_t)((v0.z - mu) * rstd * g0.z + b0.z);
        c0[3] = (bf16_t)((v0.w - mu) * rstd * g0.w + b0.w);
        c1[0] = (bf16_t)((v1.x - mu) * rstd * g1.x + b1.x);
        c1[1] = (bf16_t)((v1.y - mu) * rstd * g1.y + b1.y);
        c1[2] = (bf16_t)((v1.z - mu) * rstd * g1.z + b1.z);
        c1[3] = (bf16_t)((v1.w - mu) * rstd * g1.w + b1.w);
        bf16x4* dst = (bf16x4*)(xb + (size_t)row * D);
        dst[lane] = c0;
        dst[lane + 64] = c1;
    } else if (blk < PREP_LN_BLOCKS + PREP_CVT_BLOCKS) {
        // ---- weight cast fp32 -> bf16 ----
        int idx = (blk - PREP_LN_BLOCKS) * 256 + tid;   // [0, 196608)
        const float* src = (idx < 65536) ? Wq : (idx < 131072 ? Wk : Wv);
        int off = idx & 65535;
        float4 v = ((const float4*)src)[off];
        bf16x4 o;
        o[0] = (bf16_t)v.x; o[1] = (bf16_t)v.y; o[2] = (bf16_t)v.z; o[3] = (bf16_t)v.w;
        ((bf16x4*)wb)[idx] = o;
    } else if (blk < PREP_LN_BLOCKS + PREP_CVT_BLOCKS + PREP_AGGS_BLOCKS) {
        // ---- seq aggregation: aggS[b,col] = sum_i w_i * seq[b, QS+i, col] (unnormalized) ----
        __shared__ float red[4][64];
        int idx = blk - (PREP_LN_BLOCKS + PREP_CVT_BLOCKS);  // [0,16)
        int b = idx >> 3;
        int col = (idx & 7) * 64 + lane;
        int nv = slen[b] - QS;                                // [128, 256]
        float s2 = 0.f;
        int i0 = wid * 64, i1 = min(i0 + 64, nv);
        for (int i = i0; i < i1; ++i) {
            float wi = __expf(-0.1f * (float)(NQ - 1 - i));
            s2 += wi * seq[((size_t)(b * L + QS + i)) * D + col];
        }
        red[wid][lane] = s2;
        __syncthreads();
        if (wid == 0) {
            aggS[b * D + col] = red[0][lane] + red[1][lane] + red[2][lane] + red[3][lane];
        }
    } else {
        // ---- zero aggA (atomics accumulate into it) ----
        ((float4*)aggA)[tid & 255] = make_float4(0.f, 0.f, 0.f, 0.f);
    }
}

// ---------------- QKV GEMM via MFMA: qkv[m,n] = sum_k xb[m,k] * wb[n,k] ----------------
// M=768, N=1536, K=512. Block = 4 waves; tile 64x64; wave tile 32x32 (2x2 MFMA 16x16x32). No LDS.
__global__ __launch_bounds__(256) void qkv_gemm(const bf16_t* __restrict__ xb,
                                                const bf16_t* __restrict__ wb,
                                                float* __restrict__ qkv) {
    int m0 = blockIdx.x * 64, n0 = blockIdx.y * 64;
    int wid = threadIdx.x >> 6, lane = threadIdx.x & 63;
    int mw = m0 + (wid >> 1) * 32;
    int nw = n0 + (wid & 1) * 32;
    int mr = lane & 15, quad = lane >> 4;
    f32x4 acc00 = {}, acc01 = {}, acc10 = {}, acc11 = {};
    const bf16_t* aptr = xb + (size_t)(mw + mr) * D + quad * 8;
    const bf16_t* bptr = wb + (size_t)(nw + mr) * D + quad * 8;
#pragma unroll 4
    for (int k = 0; k < D; k += 32) {
        bf16x8 a0 = *(const bf16x8*)(aptr + k);
        bf16x8 a1 = *(const bf16x8*)(aptr + 16 * D + k);
        bf16x8 b0 = *(const bf16x8*)(bptr + k);
        bf16x8 b1 = *(const bf16x8*)(bptr + 16 * D + k);
        acc00 = __builtin_amdgcn_mfma_f32_16x16x32_bf16(a0, b0, acc00, 0, 0, 0);
        acc01 = __builtin_amdgcn_mfma_f32_16x16x32_bf16(a0, b1, acc01, 0, 0, 0);
        acc10 = __builtin_amdgcn_mfma_f32_16x16x32_bf16(a1, b0, acc10, 0, 0, 0);
        acc11 = __builtin_amdgcn_mfma_f32_16x16x32_bf16(a1, b1, acc11, 0, 0, 0);
    }
    float* base = qkv + (size_t)(mw + quad * 4) * NOUT + nw + mr;
#pragma unroll
    for (int r = 0; r < 4; ++r) {
        base[(size_t)r * NOUT +  0] = acc00[r];
        base[(size_t)r * NOUT + 16] = acc01[r];
        base[(size_t)(16 + r) * NOUT +  0] = acc10[r];
        base[(size_t)(16 + r) * NOUT + 16] = acc11[r];
    }
}

// ---------------- Attention: block = (b, q-tile of 4, head); 4 waves split keys ----------------
// Epilogue: position-weighted atomicAdd straight into aggA (no att materialization).
__global__ __launch_bounds__(256) void attn_kernel(const float* __restrict__ qkv,
                                                   const float* __restrict__ ts,
                                                   const int* __restrict__ slen,
                                                   const float* __restrict__ tw,
                                                   float* __restrict__ aggA) {
    int bid = blockIdx.x;
    int b = bid / (NQT * H);
    int rem = bid - b * (NQT * H);
    int qt = rem / H;
    int h = rem - qt * H;
    int wid = threadIdx.x >> 6;
    int lane = threadIdx.x & 63;
    int q0 = QS + qt * TQ;
    int sl = slen[b];
    if (q0 >= sl) return;               // all 4 queries padded: zero weight
    int kmin = q0 - W2;
    int kmax = min(q0 + TQ - 1 + W2, sl - 1);
    int nk = kmax - kmin + 1;           // in [5, 260]
    int chunk = (nk + 3) >> 2;          // <= 65
    int start = wid * chunk;
    int end = min(start + chunk, nk);
    int cnt = max(end - start, 0);

    __shared__ __attribute__((aligned(16))) float qv[TQ][HD];
    __shared__ __attribute__((aligned(16))) float p[4][66][TQ];
    __shared__ __attribute__((aligned(16))) float pacc[4][TQ][HD];
    __shared__ float mlm[4][TQ];
    __shared__ float mll[4][TQ];
    __shared__ float tqs[TQ];

    {
        int row = b * NROWS + (q0 + wid - ROWS0);
        qv[wid][lane] = qkv[(size_t)row * NOUT + h * HD + lane];
        if (lane == 0) tqs[wid] = ts[b * L + q0 + wid];
    }
    __syncthreads();

    float atw = fabsf(tw[0]);

    float m[TQ] = {-INFINITY, -INFINITY, -INFINITY, -INFINITY};
    float sreg[2][TQ];
#pragma unroll
    for (int it = 0; it < 2; ++it) {
        int kk = start + it * 64 + lane;
        bool act = (kk < end);
        float s[TQ] = {0.f, 0.f, 0.f, 0.f};
        if (act) {
            int k = kmin + kk;
            const float* Krow = qkv + (size_t)(b * NROWS + k - ROWS0) * NOUT + D + h * HD;
#pragma unroll
            for (int d4 = 0; d4 < 16; ++d4) {
                float4 kv = ((const float4*)Krow)[d4];
#pragma unroll
                for (int t = 0; t < TQ; ++t) {
                    float4 qq = *(const float4*)&qv[t][d4 * 4];
                    s[t] += qq.x * kv.x + qq.y * kv.y + qq.z * kv.z + qq.w * kv.w;
                }
            }
            float tk = ts[b * L + k];
#pragma unroll
            for (int t = 0; t < TQ; ++t) {
                float dt = fabsf(tqs[t] - tk);
                float bias = logf(expf(-atw * dt) + 1e-8f);
                int qa = q0 + t;
                bool valid = (k >= qa - W2) && (k <= qa + W2);
                s[t] = valid ? (s[t] * 0.125f + bias) : -INFINITY;
            }
        } else {
#pragma unroll
            for (int t = 0; t < TQ; ++t) s[t] = -INFINITY;
        }
#pragma unroll
        for (int t = 0; t < TQ; ++t) { sreg[it][t] = s[t]; m[t] = fmaxf(m[t], s[t]); }
    }
#pragma unroll
    for (int t = 0; t < TQ; ++t)
        for (int o = 32; o; o >>= 1) m[t] = fmaxf(m[t], __shfl_xor(m[t], o));

    float l[TQ] = {0.f, 0.f, 0.f, 0.f};
#pragma unroll
    for (int it = 0; it < 2; ++it) {
        int kk = start + it * 64 + lane;
        bool act = (kk < end);
        float pv[TQ];
#pragma unroll
        for (int t = 0; t < TQ; ++t) {
            float pp = (m[t] > -INFINITY) ? expf(sreg[it][t] - m[t]) : 0.0f;
            pv[t] = pp;
            l[t] += act ? pp : 0.0f;
        }
        if (act) {
            *(float4*)&p[wid][kk - start][0] = make_float4(pv[0], pv[1], pv[2], pv[3]);
        }
    }
#pragma unroll
    for (int t = 0; t < TQ; ++t)
        for (int o = 32; o; o >>= 1) l[t] += __shfl_xor(l[t], o);
    if (lane == 0) {
#pragma unroll
        for (int t = 0; t < TQ; ++t) { mlm[wid][t] = m[t]; mll[wid][t] = l[t]; }
    }

    float acc[TQ] = {0.f, 0.f, 0.f, 0.f};
    const float* Vbase = qkv + (size_t)(b * NROWS + kmin + start - ROWS0) * NOUT + 2 * D + h * HD + lane;
#pragma unroll 4
    for (int kl = 0; kl < cnt; ++kl) {
        float v = Vbase[(size_t)kl * NOUT];
        float4 pp = *(const float4*)&p[wid][kl][0];
        acc[0] += pp.x * v; acc[1] += pp.y * v; acc[2] += pp.z * v; acc[3] += pp.w * v;
    }
#pragma unroll
    for (int t = 0; t < TQ; ++t) pacc[wid][t][lane] = acc[t];
    __syncthreads();

    {
        int t = wid;
        int q = q0 + t;
        if (q < sl) {
            float m0 = mlm[0][t], m1 = mlm[1][t], m2 = mlm[2][t], m3 = mlm[3][t];
            float M = fmaxf(fmaxf(m0, m1), fmaxf(m2, m3));
            float e0 = expf(m0 - M), e1 = expf(m1 - M), e2 = expf(m2 - M), e3 = expf(m3 - M);
            float Lsum = e0 * mll[0][t] + e1 * mll[1][t] + e2 * mll[2][t] + e3 * mll[3][t];
            float o = e0 * pacc[0][t][lane] + e1 * pacc[1][t][lane]
                    + e2 * pacc[2][t][lane] + e3 * pacc[3][t][lane];
            float wq = __expf(-0.1f * (float)(L - 1 - q));
            atomicAdd(&aggA[b * D + h * HD + lane], (o / Lsum) * wq);
        }
    }
}

// ---------------- Final: out[b,d] = (aggA[b,:]·Wo[d,:] + aggS[b,d] + bo[d]*den) / (den+1e-8) ----------------
__global__ __launch_bounds__(64) void out_kernel(const float* __restrict__ aggA,
                                                 const float* __restrict__ aggS,
                                                 const float* __restrict__ Wo,
                                                 const float* __restrict__ bo,
                                                 const int* __restrict__ slen,
                                                 float* __restrict__ out) {
    int bid = blockIdx.x;
    int b = bid >> 9;
    int d = bid & 511;
    int lane = threadIdx.x;
    int nv = slen[b] - QS;
    // denominator: sum_i<nv exp(-0.1*(NQ-1-i))
    float den = 0.f;
#pragma unroll
    for (int j = 0; j < 4; ++j) {
        int i = lane * 4 + j;
        den += (i < nv) ? __expf(-0.1f * (float)(NQ - 1 - i)) : 0.0f;
    }
    for (int o = 32; o; o >>= 1) den += __shfl_xor(den, o);

    const float* wrow = Wo + (size_t)d * D;
    const float* arow = aggA + b * D;
    float acc = 0.0f;
#pragma unroll
    for (int i = 0; i < 8; ++i) {
        int j = lane + 64 * i;
        acc += arow[j] * wrow[j];
    }
    for (int o = 32; o; o >>= 1) acc += __shfl_xor(acc, o);
    if (lane == 0) {
        float inv = 1.0f / (den + 1e-8f);
        out[b * D + d] = (acc + aggS[b * D + d] + bo[d] * den) * inv;
    }
}

extern "C" void kernel_launch(void* const* d_in, const int* in_sizes, int n_in,
                              void* d_out, int out_size, void* d_ws, size_t ws_size,
                              hipStream_t stream) {
    const float* seq   = (const float*)d_in[0];
    const int*   slen  = (const int*)d_in[1];
    const float* ts    = (const float*)d_in[2];
    const float* gamma = (const float*)d_in[3];
    const float* beta  = (const float*)d_in[4];
    const float* Wq    = (const float*)d_in[5];
    const float* Wk    = (const float*)d_in[6];
    const float* Wv    = (const float*)d_in[7];
    const float* Wo    = (const float*)d_in[8];
    const float* bo    = (const float*)d_in[9];
    const float* tw    = (const float*)d_in[10];
    float* out = (float*)d_out;

    float* ws   = (float*)d_ws;
    float* qkv  = ws;                              // MROWS*NOUT = 1179648 floats
    float* aggA = qkv + (size_t)MROWS * NOUT;      // B*D = 1024
    float* aggS = aggA + B * D;                    // B*D = 1024
    bf16_t* xb  = (bf16_t*)(aggS + B * D);         // MROWS*D bf16
    bf16_t* wb  = xb + (size_t)MROWS * D;          // NOUT*D bf16

    prep_kernel<<<PREP_GRID, 256, 0, stream>>>(seq, gamma, beta, Wq, Wk, Wv, slen,
                                               xb, wb, aggA, aggS);
    dim3 ggrid(MROWS / 64, NOUT / 64);
    qkv_gemm<<<ggrid, 256, 0, stream>>>(xb, wb, qkv);
    attn_kernel<<<B * NQT * H, 256, 0, stream>>>(qkv, ts, slen, tw, aggA);
    out_kernel<<<B * D, 64, 0, stream>>>(aggA, aggS, Wo, bo, slen, out);
}

// Round 5
// 119.863 us; speedup vs baseline: 1.9364x; 1.0862x over previous
//
#include <hip/hip_runtime.h>
#include <math.h>

// Problem constants
#define B 2
#define L 2048
#define D 512
#define H 8
#define HD 64
#define W2 128            // WINDOW/2
#define NOUT (3*D)        // 1536

// Truncation: pw[l] ~ exp(-0.1*(2047-l)); seqlen in [1920,2048].
// Omitted-query relative weight <= e^-12.8 ~ 2.7e-6 -> negligible vs 1.6e-2 threshold.
#define QS 1792
#define NQ (L - QS)       // 256 queries per batch
#define ROWS0 (QS - W2)   // 1664: lowest key row needed
#define NROWS (L - ROWS0) // 384 LN/QKV rows per batch
#define MROWS (B * NROWS) // 768

#define TQ 4              // queries per attention block
#define NQT (NQ / TQ)     // 64 query tiles

typedef __bf16 bf16_t;
typedef __attribute__((ext_vector_type(4))) __bf16 bf16x4;
typedef __attribute__((ext_vector_type(8))) __bf16 bf16x8;
typedef __attribute__((ext_vector_type(4))) float f32x4;

// prep grid layout
#define PREP_LN_BLOCKS (MROWS / 4)           // 192: 4 rows/block (wave per row)
#define PREP_CVT_BLOCKS 768                  // 196608 float4s / 256
#define PREP_AGGS_BLOCKS 64                  // B * 4 rowchunks * 8 column tiles
#define PREP_GRID (PREP_LN_BLOCKS + PREP_CVT_BLOCKS + PREP_AGGS_BLOCKS)

// ---------------- prep: LN(bf16 out) + weight cast + seq aggregation ----------------
__global__ __launch_bounds__(256) void prep_kernel(const float* __restrict__ seq,
                                                   const float* __restrict__ gamma,
                                                   const float* __restrict__ beta,
                                                   const float* __restrict__ Wq,
                                                   const float* __restrict__ Wk,
                                                   const float* __restrict__ Wv,
                                                   const int* __restrict__ slen,
                                                   bf16_t* __restrict__ xb,
                                                   bf16_t* __restrict__ wb,
                                                   float* __restrict__ aggS) {
    int blk = blockIdx.x;
    int tid = threadIdx.x;
    int wid = tid >> 6, lane = tid & 63;

    if (blk < PREP_LN_BLOCKS) {
        // ---- LayerNorm: wave per row, bf16 out ----
        int row = blk * 4 + wid;
        int b = row / NROWS;
        int l = ROWS0 + (row - b * NROWS);
        const float* src = seq + ((size_t)b * L + l) * D;
        float4 v0 = ((const float4*)src)[lane];
        float4 v1 = ((const float4*)src)[lane + 64];
        float s  = v0.x + v0.y + v0.z + v0.w + v1.x + v1.y + v1.z + v1.w;
        float sq = v0.x*v0.x + v0.y*v0.y + v0.z*v0.z + v0.w*v0.w
                 + v1.x*v1.x + v1.y*v1.y + v1.z*v1.z + v1.w*v1.w;
        for (int o = 32; o; o >>= 1) { s += __shfl_xor(s, o); sq += __shfl_xor(sq, o); }
        float mu = s * (1.0f / D);
        float var = sq * (1.0f / D) - mu * mu;
        float rstd = rsqrtf(var + 1e-5f);
        float4 g0 = ((const float4*)gamma)[lane];
        float4 g1 = ((const float4*)gamma)[lane + 64];
        float4 b0 = ((const float4*)beta)[lane];
        float4 b1 = ((const float4*)beta)[lane + 64];
        bf16x4 c0, c1;
        c0[0] = (bf16_t)((v0.x - mu) * rstd * g0.x + b0.x);
        c0[1] = (bf16_t)((v0.y - mu) * rstd * g0.y + b0.y);
        c0[2] = (bf16_t)((v0.z - mu) * rstd * g0.z + b0.z);
        c0[3] = (bf16_t)((v0.w - mu) * rstd * g0.w + b0.w);
        c1[0] = (bf16_t)((v1.x - mu) * rstd * g1.x + b1.x);
        c1[1] = (bf16_t)((v1.y - mu) * rstd * g1.y + b1.y);
        c1[2] = (bf16_t)((v1.z - mu) * rstd * g1.z + b1.z);
        c1[3] = (bf16_t)((v1.w - mu) * rstd * g1.w + b1.w);
        bf16x4* dst = (bf16x4*)(xb + (size_t)row * D);
        dst[lane] = c0;
        dst[lane + 64] = c1;
    } else if (blk < PREP_LN_BLOCKS + PREP_CVT_BLOCKS) {
        // ---- weight cast fp32 -> bf16 (Wq|Wk|Wv flat) ----
        int idx = (blk - PREP_LN_BLOCKS) * 256 + tid;   // [0, 196608)
        const float* src = (idx < 65536) ? Wq : (idx < 131072 ? Wk : Wv);
        int off = idx & 65535;
        float4 v = ((const float4*)src)[off];
        bf16x4 o;
        o[0] = (bf16_t)v.x; o[1] = (bf16_t)v.y; o[2] = (bf16_t)v.z; o[3] = (bf16_t)v.w;
        ((bf16x4*)wb)[idx] = o;
    } else {
        // ---- seq aggregation: aggS[b,col] += sum_i w_i * seq[b, QS+i, col] ----
        // 64 blocks: b(1b) x rowchunk(2b) x coltile(3b); 4 waves split 16 rows each
        int idx = blk - (PREP_LN_BLOCKS + PREP_CVT_BLOCKS);  // [0,64)
        int b = idx >> 5;
        int rc = (idx >> 3) & 3;
        int ct = idx & 7;
        int col = ct * 64 + lane;
        int nv = slen[b] - QS;                                // [128, 256]
        int i0 = rc * 64 + wid * 16;
        int i1 = min(i0 + 16, nv);
        float s2 = 0.f;
#pragma unroll 4
        for (int i = i0; i < i1; ++i) {
            s2 += __expf(-0.1f * (float)(NQ - 1 - i)) * seq[((size_t)(b * L + QS + i)) * D + col];
        }
        if (i1 > i0) atomicAdd(&aggS[b * D + col], s2);
    }
}

// ---------------- QKV GEMM via MFMA -> bf16 head-major Qb/Kb/Vb ----------------
// M=768, N=1536, K=512. Block = 4 waves; block tile 32x64; wave tile 16x32. No LDS.
// Grid (24, 24) = 576 blocks.
__global__ __launch_bounds__(256) void qkv_gemm(const bf16_t* __restrict__ xb,
                                                const bf16_t* __restrict__ wb,
                                                bf16_t* __restrict__ Qb,
                                                bf16_t* __restrict__ Kb,
                                                bf16_t* __restrict__ Vb) {
    int m0 = blockIdx.x * 32, n0 = blockIdx.y * 64;
    int wid = threadIdx.x >> 6, lane = threadIdx.x & 63;
    int mw = m0 + (wid >> 1) * 16;
    int nw = n0 + (wid & 1) * 32;
    int mr = lane & 15, quad = lane >> 4;
    f32x4 acc0 = {}, acc1 = {};
    const bf16_t* aptr = xb + (size_t)(mw + mr) * D + quad * 8;
    const bf16_t* bptr = wb + (size_t)(nw + mr) * D + quad * 8;
#pragma unroll 8
    for (int k = 0; k < D; k += 32) {
        bf16x8 a  = *(const bf16x8*)(aptr + k);
        bf16x8 b0 = *(const bf16x8*)(bptr + k);
        bf16x8 b1 = *(const bf16x8*)(bptr + 16 * D + k);
        acc0 = __builtin_amdgcn_mfma_f32_16x16x32_bf16(a, b0, acc0, 0, 0, 0);
        acc1 = __builtin_amdgcn_mfma_f32_16x16x32_bf16(a, b1, acc1, 0, 0, 0);
    }
    // C layout: row m = mw + quad*4 + rr, col n = nw + mr (acc0) / nw + 16 + mr (acc1)
    int sec = n0 >> 9;                 // 0=Q, 1=K, 2=V
    int h = (n0 >> 6) & 7;
    int d0 = nw & 63;
    bf16_t* dstbase = (sec == 0) ? Qb : (sec == 1 ? Kb : Vb);
    int m = mw + quad * 4;
    int b = m / NROWS;                 // rows m..m+3 stay within one batch (32 | 384)
    int r = m - b * NROWS;
    bf16_t* dst = dstbase + ((size_t)(b * H + h) * NROWS + r) * HD + d0 + mr;
#pragma unroll
    for (int rr = 0; rr < 4; ++rr) {
        dst[(size_t)rr * HD]      = (bf16_t)acc0[rr];
        dst[(size_t)rr * HD + 16] = (bf16_t)acc1[rr];
    }
}

// ---------------- Attention: block = (b, q-tile of 4, head); 4 waves split keys ----------------
// bf16 head-major K/V; epilogue = position-weighted atomicAdd into aggA.
__global__ __launch_bounds__(256) void attn_kernel(const bf16_t* __restrict__ Qb,
                                                   const bf16_t* __restrict__ Kb,
                                                   const bf16_t* __restrict__ Vb,
                                                   const float* __restrict__ ts,
                                                   const int* __restrict__ slen,
                                                   const float* __restrict__ tw,
                                                   float* __restrict__ aggA) {
    int bid = blockIdx.x;
    int b = bid / (NQT * H);
    int rem = bid - b * (NQT * H);
    int qt = rem / H;
    int h = rem - qt * H;
    int wid = threadIdx.x >> 6;
    int lane = threadIdx.x & 63;
    int q0 = QS + qt * TQ;
    int sl = slen[b];
    if (q0 >= sl) return;               // uniform: all 4 queries padded (zero weight)
    int kmin = q0 - W2;
    int kmax = min(q0 + TQ - 1 + W2, sl - 1);
    int nk = kmax - kmin + 1;           // in [129, 260]
    int chunk = (nk + 3) >> 2;          // <= 65
    int start = wid * chunk;
    int end = min(start + chunk, nk);
    int cnt = max(end - start, 0);

    __shared__ __attribute__((aligned(16))) float qv[TQ][HD];
    __shared__ __attribute__((aligned(16))) float p[4][66][TQ];
    __shared__ __attribute__((aligned(16))) float pacc[4][TQ][HD];
    __shared__ float mlm[4][TQ];
    __shared__ float mll[4][TQ];
    __shared__ float tqs[TQ];

    const size_t headbase = (size_t)(b * H + h) * NROWS;   // row offset into Qb/Kb/Vb

    {
        // wave wid loads query row (q0+wid)'s 64 dims
        int qr = q0 + wid - ROWS0;
        qv[wid][lane] = (float)Qb[(headbase + qr) * HD + lane];
        if (lane == 0) tqs[wid] = ts[b * L + q0 + wid];
    }
    __syncthreads();

    float atw = fabsf(tw[0]);

    // ---- scores: lane = key; <=2 batches per wave ----
    float m[TQ] = {-INFINITY, -INFINITY, -INFINITY, -INFINITY};
    float sreg[2][TQ];
#pragma unroll
    for (int it = 0; it < 2; ++it) {
        int kk = start + it * 64 + lane;
        bool act = (kk < end);
        float s[TQ] = {0.f, 0.f, 0.f, 0.f};
        if (act) {
            int k = kmin + kk;
            const bf16_t* Krow = Kb + (headbase + (k - ROWS0)) * HD;
#pragma unroll
            for (int d8 = 0; d8 < 8; ++d8) {
                bf16x8 kv = *(const bf16x8*)(Krow + d8 * 8);
                float kf0 = (float)kv[0], kf1 = (float)kv[1], kf2 = (float)kv[2], kf3 = (float)kv[3];
                float kf4 = (float)kv[4], kf5 = (float)kv[5], kf6 = (float)kv[6], kf7 = (float)kv[7];
#pragma unroll
                for (int t = 0; t < TQ; ++t) {
                    const float* qq = &qv[t][d8 * 8];
                    s[t] += qq[0]*kf0 + qq[1]*kf1 + qq[2]*kf2 + qq[3]*kf3
                          + qq[4]*kf4 + qq[5]*kf5 + qq[6]*kf6 + qq[7]*kf7;
                }
            }
            float tk = ts[b * L + k];
#pragma unroll
            for (int t = 0; t < TQ; ++t) {
                float dt = fabsf(tqs[t] - tk);
                float bias = logf(expf(-atw * dt) + 1e-8f);
                int qa = q0 + t;
                bool valid = (k >= qa - W2) && (k <= qa + W2);
                s[t] = valid ? (s[t] * 0.125f + bias) : -INFINITY;
            }
        } else {
#pragma unroll
            for (int t = 0; t < TQ; ++t) s[t] = -INFINITY;
        }
#pragma unroll
        for (int t = 0; t < TQ; ++t) { sreg[it][t] = s[t]; m[t] = fmaxf(m[t], s[t]); }
    }
#pragma unroll
    for (int t = 0; t < TQ; ++t)
        for (int o = 32; o; o >>= 1) m[t] = fmaxf(m[t], __shfl_xor(m[t], o));

    float l[TQ] = {0.f, 0.f, 0.f, 0.f};
#pragma unroll
    for (int it = 0; it < 2; ++it) {
        int kk = start + it * 64 + lane;
        bool act = (kk < end);
        float pv[TQ];
#pragma unroll
        for (int t = 0; t < TQ; ++t) {
            float pp = (m[t] > -INFINITY) ? expf(sreg[it][t] - m[t]) : 0.0f;
            pv[t] = pp;
            l[t] += act ? pp : 0.0f;
        }
        if (act) {
            *(float4*)&p[wid][kk - start][0] = make_float4(pv[0], pv[1], pv[2], pv[3]);
        }
    }
#pragma unroll
    for (int t = 0; t < TQ; ++t)
        for (int o = 32; o; o >>= 1) l[t] += __shfl_xor(l[t], o);
    if (lane == 0) {
#pragma unroll
        for (int t = 0; t < TQ; ++t) { mlm[wid][t] = m[t]; mll[wid][t] = l[t]; }
    }

    // ---- P·V over own chunk: lane = dim, coalesced 128B bf16 V rows ----
    float acc[TQ] = {0.f, 0.f, 0.f, 0.f};
    const bf16_t* Vbase = Vb + (headbase + (kmin + start - ROWS0)) * HD + lane;
#pragma unroll 4
    for (int kl = 0; kl < cnt; ++kl) {
        float v = (float)Vbase[(size_t)kl * HD];
        float4 pp = *(const float4*)&p[wid][kl][0];
        acc[0] += pp.x * v; acc[1] += pp.y * v; acc[2] += pp.z * v; acc[3] += pp.w * v;
    }
#pragma unroll
    for (int t = 0; t < TQ; ++t) pacc[wid][t][lane] = acc[t];
    __syncthreads();

    // ---- merge partials: wave = query, lane = dim; weighted atomic epilogue ----
    {
        int t = wid;
        int q = q0 + t;
        if (q < sl) {
            float m0 = mlm[0][t], m1 = mlm[1][t], m2 = mlm[2][t], m3 = mlm[3][t];
            float M = fmaxf(fmaxf(m0, m1), fmaxf(m2, m3));
            float e0 = expf(m0 - M), e1 = expf(m1 - M), e2 = expf(m2 - M), e3 = expf(m3 - M);
            float Lsum = e0 * mll[0][t] + e1 * mll[1][t] + e2 * mll[2][t] + e3 * mll[3][t];
            float o = e0 * pacc[0][t][lane] + e1 * pacc[1][t][lane]
                    + e2 * pacc[2][t][lane] + e3 * pacc[3][t][lane];
            float wq = __expf(-0.1f * (float)(L - 1 - q));
            atomicAdd(&aggA[b * D + h * HD + lane], (o / Lsum) * wq);
        }
    }
}

// ---------------- Final: out[b,d] = (aggA·Wo[d,:] + aggS[b,d] + bo[d]*den) / (den+1e-8) ----------------
__global__ __launch_bounds__(64) void out_kernel(const float* __restrict__ aggA,
                                                 const float* __restrict__ aggS,
                                                 const float* __restrict__ Wo,
                                                 const float* __restrict__ bo,
                                                 const int* __restrict__ slen,
                                                 float* __restrict__ out) {
    int bid = blockIdx.x;
    int b = bid >> 9;
    int d = bid & 511;
    int lane = threadIdx.x;
    int nv = slen[b] - QS;
    float den = 0.f;
#pragma unroll
    for (int j = 0; j < 4; ++j) {
        int i = lane * 4 + j;
        den += (i < nv) ? __expf(-0.1f * (float)(NQ - 1 - i)) : 0.0f;
    }
    for (int o = 32; o; o >>= 1) den += __shfl_xor(den, o);

    const float* wrow = Wo + (size_t)d * D;
    const float* arow = aggA + b * D;
    float acc = 0.0f;
#pragma unroll
    for (int i = 0; i < 8; ++i) {
        int j = lane + 64 * i;
        acc += arow[j] * wrow[j];
    }
    for (int o = 32; o; o >>= 1) acc += __shfl_xor(acc, o);
    if (lane == 0) {
        float inv = 1.0f / (den + 1e-8f);
        out[b * D + d] = (acc + aggS[b * D + d] + bo[d] * den) * inv;
    }
}

extern "C" void kernel_launch(void* const* d_in, const int* in_sizes, int n_in,
                              void* d_out, int out_size, void* d_ws, size_t ws_size,
                              hipStream_t stream) {
    const float* seq   = (const float*)d_in[0];
    const int*   slen  = (const int*)d_in[1];
    const float* ts    = (const float*)d_in[2];
    const float* gamma = (const float*)d_in[3];
    const float* beta  = (const float*)d_in[4];
    const float* Wq    = (const float*)d_in[5];
    const float* Wk    = (const float*)d_in[6];
    const float* Wv    = (const float*)d_in[7];
    const float* Wo    = (const float*)d_in[8];
    const float* bo    = (const float*)d_in[9];
    const float* tw    = (const float*)d_in[10];
    float* out = (float*)d_out;

    float* ws    = (float*)d_ws;
    float* aggA  = ws;                                  // B*D floats
    float* aggS  = aggA + B * D;                        // B*D floats
    bf16_t* xb   = (bf16_t*)(aggS + B * D);             // MROWS*D bf16
    bf16_t* wb   = xb + (size_t)MROWS * D;              // NOUT*D bf16
    bf16_t* Qb   = wb + (size_t)NOUT * D;               // B*H*NROWS*HD bf16
    bf16_t* Kb   = Qb + (size_t)B * H * NROWS * HD;
    bf16_t* Vb   = Kb + (size_t)B * H * NROWS * HD;

    hipMemsetAsync(aggA, 0, 2 * B * D * sizeof(float), stream);
    prep_kernel<<<PREP_GRID, 256, 0, stream>>>(seq, gamma, beta, Wq, Wk, Wv, slen,
                                               xb, wb, aggS);
    dim3 ggrid(MROWS / 32, NOUT / 64);
    qkv_gemm<<<ggrid, 256, 0, stream>>>(xb, wb, Qb, Kb, Vb);
    attn_kernel<<<B * NQT * H, 256, 0, stream>>>(Qb, Kb, Vb, ts, slen, tw, aggA);
    out_kernel<<<B * D, 64, 0, stream>>>(aggA, aggS, Wo, bo, slen, out);
}